// Round 6
// baseline (74.415 us; speedup 1.0000x reference)
//
#include <hip/hip_runtime.h>
#include <float.h>

#define OUTP 7
#define NCH 256
#define FH 50
#define FW 50
#define CHW (FH * FW)

// One wave per (roi, 4-channel group). Wave-uniform tier on region width w:
//   w<=16: 4 channels in parallel (lane = ch*16+col), 1 pass
//   w<=32: 2 channels in parallel (lane = ch*32+col), 2 passes
//   else : 1 channel, 4 passes
// Fixes v5's 27% avg lane utilization and amortizes per-ROI setup 4x.
// Clamped fixed-unroll row-bins kept from v5 (bin height <= 4 for h<=21,
// <= 8 for h<=50; duplicates load identical addresses, L1 broadcast).
__global__ __launch_bounds__(256) void roi_pool_v6(
    const float* __restrict__ features,   // (B,256,50,50)
    const float* __restrict__ cat_rois,   // (N,5): im,x1,y1,x2,y2
    float* __restrict__ out)              // (N,256,7,7)
{
    __shared__ float rowmax[4][OUTP][66];   // per-wave slice, 7392 B

    const int lane = threadIdx.x & 63;
    const int quad = threadIdx.x >> 6;
    const int n    = blockIdx.x >> 4;                  // 16 blocks per ROI
    const int c0   = ((blockIdx.x & 15) << 4) + (quad << 2);  // 4 ch per wave

    const float* r5 = cat_rois + n * 5;
    const int im = __builtin_amdgcn_readfirstlane((int)rintf(r5[0]));
    const int x1 = __builtin_amdgcn_readfirstlane((int)rintf(r5[1] * 0.0625f));
    const int y1 = __builtin_amdgcn_readfirstlane((int)rintf(r5[2] * 0.0625f));
    const int x2 = __builtin_amdgcn_readfirstlane((int)rintf(r5[3] * 0.0625f));
    const int y2 = __builtin_amdgcn_readfirstlane((int)rintf(r5[4] * 0.0625f));

    const int h = y2 - y1 + 1;    // region fully in-bounds (clamps no-ops)
    const int w = x2 - x1 + 1;

    const int lwshift = (w <= 16) ? 4 : (w <= 32) ? 5 : 6;  // wave-uniform
    const int LW      = 1 << lwshift;          // lanes per channel
    const int CP      = 64 >> lwshift;         // channels in parallel
    const int npass   = 4 >> (6 - lwshift);    // 1,2,4
    const int ch_sub  = lane >> lwshift;
    const int col     = lane & (LW - 1);

    const size_t im_base = (size_t)(im * NCH) * CHW + y1 * FW + x1;

    for (int pass = 0; pass < npass; ++pass) {
        const int cc = c0 + pass * CP + ch_sub;
        const float* base = features + im_base + (size_t)cc * CHW;

        float rm[OUTP];
        #pragma unroll
        for (int i = 0; i < OUTP; ++i) rm[i] = -FLT_MAX;

        if (col < w) {
            if (h <= 21) {
                // bin height <= 4: fixed clamped loads, all independent
                #pragma unroll
                for (int i = 0; i < OUTP; ++i) {
                    const int ys  = i * h / OUTP;
                    const int ye1 = ((i + 1) * h + OUTP - 1) / OUTP - 1;
                    float v0 = base[ys * FW + col];
                    float v1 = base[min(ys + 1, ye1) * FW + col];
                    float v2 = base[min(ys + 2, ye1) * FW + col];
                    float v3 = base[min(ys + 3, ye1) * FW + col];
                    rm[i] = fmaxf(fmaxf(v0, v1), fmaxf(v2, v3));
                }
            } else {
                // h in (21,50]: bin height <= 8
                #pragma unroll
                for (int i = 0; i < OUTP; ++i) {
                    const int ys  = i * h / OUTP;
                    const int ye1 = ((i + 1) * h + OUTP - 1) / OUTP - 1;
                    float v[8];
                    #pragma unroll
                    for (int k = 0; k < 8; ++k)
                        v[k] = base[min(ys + k, ye1) * FW + col];
                    rm[i] = fmaxf(fmaxf(fmaxf(v[0], v[1]), fmaxf(v[2], v[3])),
                                  fmaxf(fmaxf(v[4], v[5]), fmaxf(v[6], v[7])));
                }
            }
        }

        #pragma unroll
        for (int i = 0; i < OUTP; ++i)
            rowmax[quad][i][lane] = rm[i];

        __syncthreads();   // uniform per block (same ROI -> same npass)

        if (lane < OUTP * OUTP) {
            const int i  = lane / OUTP;
            const int j  = lane - i * OUTP;
            const int xs = j * w / OUTP;
            const int xe = ((j + 1) * w + OUTP - 1) / OUTP;   // <= w <= LW
            for (int cs = 0; cs < CP; ++cs) {
                const float* rp = &rowmax[quad][i][cs << lwshift];
                float m = -FLT_MAX;
                for (int x = xs; x < xe; ++x)
                    m = fmaxf(m, rp[x]);
                out[((size_t)n * NCH + (c0 + pass * CP + cs)) * (OUTP * OUTP)
                    + lane] = m;
            }
        }

        __syncthreads();   // WAR: before next pass overwrites rowmax
    }
}

extern "C" void kernel_launch(void* const* d_in, const int* in_sizes, int n_in,
                              void* d_out, int out_size, void* d_ws, size_t ws_size,
                              hipStream_t stream) {
    const float* features = (const float*)d_in[0];
    const float* cat_rois = (const float*)d_in[1];
    float* out = (float*)d_out;

    const int N = in_sizes[1] / 5;        // 128 ROIs
    dim3 grid(N * (NCH / 16));            // 2048 blocks, 4 waves, 16 ch each
    roi_pool_v6<<<grid, 256, 0, stream>>>(features, cat_rois, out);
}